// Round 16
// baseline (62.854 us; speedup 1.0000x reference)
//
#include <hip/hip_runtime.h>
#include <math.h>
#include <limits.h>

#define NQ     64
#define NE     10000
#define K      10
#define NBLK   625         // kernel-1 blocks; 16 entities each (625*16 = 10000)
#define EPB    16          // entities per block
#define TPB    512         // 8 waves; wave owns 2 entities x all 64 queries
#define EPW    2           // entities per wave
#define SLOT   11          // padded merge-slot stride (entries)
#define SCALE  8388608.0f  // 2^23: inputs are multiples of 2^-23 in [0,1) -> exact u32

// ---------- comparator (lax.top_k: ties -> lower index first) ----------
// BOT lists store NEGATED values, so this single comparator serves both directions.
__device__ __forceinline__ bool better_top(double v, int i, double v2, int i2) {
    return (v > v2) || (v == v2 && i < i2);
}

// merge two sorted K-lists in LDS (u16 indices; slot stride SLOT) -> into A
__device__ __forceinline__ void merge_slots16(double* Mv, unsigned short* Mi, int A, int B) {
    double ov[K]; unsigned short oi[K];
    int a = 0, b = 0;
#pragma unroll
    for (int o = 0; o < K; ++o) {
        double va = Mv[A * SLOT + a]; int ia = Mi[A * SLOT + a];
        double vb = Mv[B * SLOT + b]; int ib = Mi[B * SLOT + b];
        bool pick = better_top(va, ia, vb, ib);
        ov[o] = pick ? va : vb;
        oi[o] = (unsigned short)(pick ? ia : ib);
        if (pick) ++a; else ++b;
    }
#pragma unroll
    for (int o = 0; o < K; ++o) { Mv[A * SLOT + o] = ov[o]; Mi[A * SLOT + o] = oi[o]; }
}

// merge LDS K-list (stride K) with a sorted global K-list -> back into LDS
__device__ __forceinline__ void merge_lds_global(double* Lv, int* Li, int slot,
                                                 const double* __restrict__ V,
                                                 const unsigned short* __restrict__ I,
                                                 int src) {
    double ov[K]; int oi[K];
    int a = 0, b = 0;
#pragma unroll
    for (int o = 0; o < K; ++o) {
        double va = Lv[slot * K + a]; int ia = Li[slot * K + a];
        double vb = V[(size_t)src * K + b]; int ib = (int)I[(size_t)src * K + b];
        bool pick = better_top(va, ia, vb, ib);
        ov[o] = pick ? va : vb;
        oi[o] = pick ? ia : ib;
        if (pick) ++a; else ++b;
    }
#pragma unroll
    for (int o = 0; o < K; ++o) { Lv[slot * K + o] = ov[o]; Li[slot * K + o] = oi[o]; }
}

// compare-exchange (static indices -> stays in registers)
#define CSWAP(v, ii, A, B)                                                 \
    {                                                                      \
        bool c_ = better_top(v[B], ii[B], v[A], ii[A]);                    \
        double tv_ = c_ ? v[B] : v[A]; double uv_ = c_ ? v[A] : v[B];      \
        int    ti_ = c_ ? ii[B] : ii[A]; int ui_ = c_ ? ii[A] : ii[B];     \
        v[A] = tv_; v[B] = uv_; ii[A] = ti_; ii[B] = ui_;                  \
    }

// ---------------- kernel 0: exact u32 entity row sums (wave per row) ----------------
__global__ __launch_bounds__(256) void ent_sums(const float* __restrict__ E,
                                                unsigned* __restrict__ Se) {
    const int w = threadIdx.x >> 6, l = threadIdx.x & 63;
    const int j = blockIdx.x * 4 + w;          // 2500 blocks * 4 waves = 10000 rows
    float4 v = reinterpret_cast<const float4*>(E)[(size_t)j * 64 + l];
    unsigned s = (unsigned)(v.x * SCALE) + (unsigned)(v.y * SCALE)
               + (unsigned)(v.z * SCALE) + (unsigned)(v.w * SCALE);
#pragma unroll
    for (int m = 1; m < 64; m <<= 1) s += (unsigned)__shfl_xor((int)s, m, 64);
    if (l == 0) Se[j] = s;
}

// ---------------- kernel 1: lane = query, entities in VGPRs, 5000 waves ----------------
// 625 blocks x 512 thr (8 waves). Block b: entities [b*16, b*16+16); wave w owns 2.
// Lane l = query l. Entity dims broadcast from VGPRs via v_readlane (uniform lane g).
// LDS (static, 66560 B -> 2 blocks/CU):
//   QT uint4[64*65]: QT[g*65 + q], +1 slot row pad.
//   merge overlay (re-used per direction): Mv dbl[512*SLOT] @0 (45056),
//                                          Mi u16[512*SLOT] @45056 (11264)
__global__ __launch_bounds__(TPB, 2) void jac_part(
        const float* __restrict__ Q, const float* __restrict__ E,
        const unsigned* __restrict__ Se,
        double* __restrict__ pvT, double* __restrict__ pvB,
        unsigned short* __restrict__ piT, unsigned short* __restrict__ piB) {
    __shared__ uint4 QT[64 * 65];   // 66560 B

    const int t = threadIdx.x;
    const int l = t & 63;          // query index
    const int w = t >> 6;          // wave 0..7
    const int b = blockIdx.x;
    const int ebase = b * EPB + w * EPW;

    const float4* E4 = (const float4*)E;
    const float4* Q4 = (const float4*)Q;

    // ---- issue entity-row loads first (latency hides under QT staging) ----
    float4 er[EPW];
#pragma unroll
    for (int s = 0; s < EPW; ++s) er[s] = E4[(size_t)(ebase + s) * 64 + l];  // coalesced
    unsigned se[EPW];
#pragma unroll
    for (int s = 0; s < EPW; ++s) se[s] = Se[ebase + s];                      // uniform

    // ---- stage QT (coalesced global -> transposed padded LDS, u32) ----
#pragma unroll
    for (int it = 0; it < 8; ++it) {
        const int f = t + TPB * it;            // flat float4 index
        float4 v = Q4[f];
        uint4 u;
        u.x = (unsigned)(v.x * SCALE); u.y = (unsigned)(v.y * SCALE);
        u.z = (unsigned)(v.z * SCALE); u.w = (unsigned)(v.w * SCALE);
        QT[(f & 63) * 65 + (f >> 6)] = u;      // [group][query]
    }

    uint4 eu[EPW];
#pragma unroll
    for (int s = 0; s < EPW; ++s) {
        eu[s].x = (unsigned)(er[s].x * SCALE); eu[s].y = (unsigned)(er[s].y * SCALE);
        eu[s].z = (unsigned)(er[s].z * SCALE); eu[s].w = (unsigned)(er[s].w * SCALE);
    }
    __syncthreads();

    // ---- g-loop: 1 LDS read per g; entity dims via readlane (SGPR broadcast) ----
    unsigned a0[EPW], a1[EPW];
#pragma unroll
    for (int s = 0; s < EPW; ++s) { a0[s] = 0; a1[s] = 0; }
    unsigned sq = 0;

#pragma unroll 8
    for (int g = 0; g < 64; ++g) {
        uint4 qv = QT[g * 65 + l];             // lane-contiguous 16B: conflict-free
        sq += (qv.x + qv.y) + (qv.z + qv.w);   // exact query row sum
#pragma unroll
        for (int s = 0; s < EPW; ++s) {
            unsigned ex = (unsigned)__builtin_amdgcn_readlane((int)eu[s].x, g);
            unsigned ey = (unsigned)__builtin_amdgcn_readlane((int)eu[s].y, g);
            unsigned ez = (unsigned)__builtin_amdgcn_readlane((int)eu[s].z, g);
            unsigned ew = (unsigned)__builtin_amdgcn_readlane((int)eu[s].w, g);
            a0[s] += min(qv.x, ex) + min(qv.y, ey);
            a1[s] += min(qv.z, ez) + min(qv.w, ew);
        }
    }

    // ---- candidates: top (av) and negated bot (bv); 2 elements -> 1 cswap each ----
    double av[EPW]; int ai[EPW]; double bv[EPW]; int bi[EPW];
#pragma unroll
    for (int s = 0; s < EPW; ++s) {
        unsigned inter = a0[s] + a1[s];
        unsigned uni   = sq + se[s] - inter;   // min+max == q+e exactly; < 2^32
        // num & den both scaled by 2^23 -> IEEE f64 quotient identical to unscaled
        double jac = (double)inter / (double)uni;
        av[s] = jac;  ai[s] = ebase + s;
        bv[s] = -jac; bi[s] = ebase + s;
    }
    CSWAP(av, ai, 0, 1)
    CSWAP(bv, bi, 0, 1)

    // ---- merge 8 wave-lists per query, two sequential passes in one overlay ----
    __syncthreads();                           // all QT reads done -> overlay
    double*         Mv = (double*)&QT[0];
    unsigned short* Mi = (unsigned short*)((char*)&QT[0] + 45056);
    const int slot = w * 64 + l;

    // TOP pass
#pragma unroll
    for (int o = 0; o < EPW; ++o) { Mv[slot * SLOT + o] = av[o]; Mi[slot * SLOT + o] = (unsigned short)ai[o]; }
#pragma unroll
    for (int o = EPW; o < K; ++o) { Mv[slot * SLOT + o] = -INFINITY; Mi[slot * SLOT + o] = 0xFFFFu; }
    __syncthreads();
    for (int s = 4; s >= 1; s >>= 1) {
        if (w < s) merge_slots16(Mv, Mi, w * 64 + l, (w + s) * 64 + l);
        __syncthreads();
    }
    if (w == 0) {
        const size_t off = ((size_t)l * NBLK + b) * K;   // query-major
#pragma unroll
        for (int o = 0; o < K; ++o) { pvT[off + o] = Mv[l * SLOT + o]; piT[off + o] = Mi[l * SLOT + o]; }
    }
    __syncthreads();

    // BOT pass (negated values, same comparator)
#pragma unroll
    for (int o = 0; o < EPW; ++o) { Mv[slot * SLOT + o] = bv[o]; Mi[slot * SLOT + o] = (unsigned short)bi[o]; }
#pragma unroll
    for (int o = EPW; o < K; ++o) { Mv[slot * SLOT + o] = -INFINITY; Mi[slot * SLOT + o] = 0xFFFFu; }
    __syncthreads();
    for (int s = 4; s >= 1; s >>= 1) {
        if (w < s) merge_slots16(Mv, Mi, w * 64 + l, (w + s) * 64 + l);
        __syncthreads();
    }
    if (w == 0) {
        const size_t off = ((size_t)l * NBLK + b) * K;   // query-major
#pragma unroll
        for (int o = 0; o < K; ++o) { pvB[off + o] = Mv[l * SLOT + o]; piB[off + o] = Mi[l * SLOT + o]; }
    }
}

// ---------------- kernel 2: fold 625->256 lists, then 10-round max-extraction ----------------
// grid = 128: block -> query q = bid>>1, dir = bid&1. BOT values arrive pre-negated.
__global__ __launch_bounds__(256) void final_extract(
        const double* __restrict__ pvT, const double* __restrict__ pvB,
        const unsigned short* __restrict__ piT, const unsigned short* __restrict__ piB,
        int* __restrict__ out) {
    __shared__ double Lv[256 * K];      // 20480 B
    __shared__ int    Li[256 * K];      // 10240 B
    __shared__ double Wv[4];
    __shared__ int    Wi[4], Wo[4];
    __shared__ int    res[K];

    const int bid = blockIdx.x;
    const int q   = bid >> 1;
    const bool top = (bid & 1) == 0;
    const int t   = threadIdx.x;
    const int l   = t & 63;
    const int w   = t >> 6;

    const double*         V = (top ? pvT : pvB) + (size_t)q * NBLK * K;
    const unsigned short* I = (top ? piT : piB) + (size_t)q * NBLK * K;

    // load list t, then fold lists t+256, t+512 (if present) via LDS merges
#pragma unroll
    for (int o = 0; o < K; ++o) { Lv[t * K + o] = V[(size_t)t * K + o]; Li[t * K + o] = (int)I[(size_t)t * K + o]; }
    for (int src = t + 256; src < NBLK; src += 256)
        merge_lds_global(Lv, Li, t, V, I, src);
    __syncthreads();

    // per-thread head; each of the 256 slots is sorted best-first
    int h = 0;
    double hv = Lv[t * K];
    int    hi = Li[t * K];

    for (int r = 0; r < K; ++r) {
        // wave argmax butterfly on (val, entity-idx, owner)
        double v = hv; int idx = hi; int own = t;
#pragma unroll
        for (int m = 1; m < 64; m <<= 1) {
            double ov = __shfl_xor(v, m, 64);
            int    oi = __shfl_xor(idx, m, 64);
            int    oo = __shfl_xor(own, m, 64);
            if (better_top(ov, oi, v, idx)) { v = ov; idx = oi; own = oo; }
        }
        if (l == 0) { Wv[w] = v; Wi[w] = idx; Wo[w] = own; }
        __syncthreads();
        double gv = Wv[0]; int gi = Wi[0], go = Wo[0];
#pragma unroll
        for (int ww = 1; ww < 4; ++ww)
            if (better_top(Wv[ww], Wi[ww], gv, gi)) { gv = Wv[ww]; gi = Wi[ww]; go = Wo[ww]; }
        if (t == go) {          // winner advances its head (LDS dynamic index: fine)
            ++h;
            bool ok = h < K;
            hv = ok ? Lv[t * K + h] : -INFINITY;
            hi = ok ? Li[t * K + h] : INT_MAX;
        }
        if (t == 0) res[r] = gi;
        __syncthreads();        // protect Wv/Wi/Wo before next round's overwrite
    }

    if (t < K) out[(top ? 0 : NQ * K) + q * K + t] = res[t];
}

extern "C" void kernel_launch(void* const* d_in, const int* in_sizes, int n_in,
                              void* d_out, int out_size, void* d_ws, size_t ws_size,
                              hipStream_t stream) {
    const float* Q = (const float*)d_in[0];   // [64, 256]
    const float* E = (const float*)d_in[1];   // [10000, 256]
    int* out = (int*)d_out;                   // 640 top idx + 640 bot idx

    // workspace: Se(u32) + query-major partial lists, u16 indices (8.04 MB)
    char* ws = (char*)d_ws;
    unsigned*       Se  = (unsigned*)(ws);            // 40,960 (padded)
    double*         pvT = (double*)(ws + 40960);      // 64*625*10*8 = 3,200,000
    double*         pvB = (double*)(ws + 3240960);    // 3,200,000 (negated values)
    unsigned short* piT = (unsigned short*)(ws + 6440960);  // 800,000
    unsigned short* piB = (unsigned short*)(ws + 7240960);  // 800,000

    hipLaunchKernelGGL(ent_sums, dim3(NE / 4), dim3(256), 0, stream, E, Se);
    hipLaunchKernelGGL(jac_part, dim3(NBLK), dim3(TPB), 0, stream,
                       Q, E, Se, pvT, pvB, piT, piB);
    hipLaunchKernelGGL(final_extract, dim3(NQ * 2), dim3(256), 0, stream,
                       pvT, pvB, piT, piB, out);
}